// Round 2
// baseline (330.668 us; speedup 1.0000x reference)
//
#include <hip/hip_runtime.h>
#include <hip/hip_bf16.h>
#include <stdint.h>

#define CH 256
#define D8 32
#define NN 4096

typedef __attribute__((ext_vector_type(8))) short short8;
typedef __attribute__((ext_vector_type(4))) float f32x4;

#define MFMA16(a,b,c) __builtin_amdgcn_mfma_f32_16x16x32_bf16(a,b,c,0,0,0)

static __device__ __forceinline__ short f2bf(float f) {
  union { float f; uint32_t u; } v; v.f = f;
  uint32_t r = v.u + 0x7fffu + ((v.u >> 16) & 1u);
  return (short)(r >> 16);
}
static __device__ __forceinline__ float bf2f(short h) {
  union { float f; uint32_t u; } v; v.u = ((uint32_t)(uint16_t)h) << 16;
  return v.f;
}

// ---------------- prep: x transpose->bf16 + weight convert ----------------
__global__ __launch_bounds__(256) void prep_kernel(
    const float* __restrict__ x,
    const float* __restrict__ wq, const float* __restrict__ bq,
    const float* __restrict__ wk, const float* __restrict__ bk,
    const float* __restrict__ wv, const float* __restrict__ bv,
    short* __restrict__ xT, short* __restrict__ WQb,
    short* __restrict__ WKb, short* __restrict__ WVb,
    float* __restrict__ BQ, float* __restrict__ BK, float* __restrict__ BV)
{
  int blk = blockIdx.x, t = threadIdx.x;
  if (blk >= 1024) {
    int idx = (blk - 1024) * 256 + t;            // 0..2047
    const float LOG2E = 1.4426950408889634f;     // fold into Q so exp2 == exp
    for (int i = idx; i < D8 * CH; i += 2048) WQb[i] = f2bf(wq[i] * LOG2E);
    for (int i = idx; i < D8 * CH; i += 2048) WKb[i] = f2bf(wk[i]);
    for (int i = idx; i < CH * CH; i += 2048) WVb[i] = f2bf(wv[i]);
    if (idx < D8) { BQ[idx] = bq[idx] * LOG2E; BK[idx] = bk[idx]; }
    if (idx < CH) BV[idx] = bv[idx];
    return;
  }
  int b = blk >> 8, ct = (blk >> 6) & 3, nt = blk & 63;
  __shared__ short T[64][65];                    // +1 pad: conflict-free transpose
  int j = t & 63, i0 = t >> 6;
  const float* xb = x + ((size_t)b * CH + ct * 64) * NN + nt * 64;
  #pragma unroll
  for (int k = 0; k < 16; ++k) {
    int i = k * 4 + i0;
    T[i][j] = f2bf(xb[(size_t)i * NN + j]);      // coalesced over n
  }
  __syncthreads();
  short* xTb = xT + ((size_t)b * NN + nt * 64) * CH + ct * 64;
  #pragma unroll
  for (int k = 0; k < 16; ++k) {
    int n = k * 4 + i0;
    xTb[(size_t)n * CH + j] = T[j][n];           // coalesced over c
  }
}

// ---------------- proj: Qhi/lo, Khi/lo (n,32) and V (c,n) in bf16 ----------------
__global__ __launch_bounds__(256) void proj_kernel(
    const short* __restrict__ xT,
    const short* __restrict__ WQb, const short* __restrict__ WKb,
    const short* __restrict__ WVb,
    const float* __restrict__ BQ, const float* __restrict__ BK,
    const float* __restrict__ BV,
    short* __restrict__ Qh, short* __restrict__ Ql,
    short* __restrict__ Kh, short* __restrict__ Kl,
    short* __restrict__ Vo)
{
  int blk = blockIdx.x, t = threadIdx.x;
  int b = blk >> 6, pt = blk & 63;
  int w = t >> 6, lane = t & 63, g = lane >> 4, lr = lane & 15;
  int p0 = pt * 64 + w * 16;
  __shared__ short Vl[CH][66];                   // pad 66: conflict-free

  const short* xrow = xT + ((size_t)b * NN + p0 + lr) * CH + g * 8;
  short8 a[8];
  #pragma unroll
  for (int s = 0; s < 8; ++s) a[s] = *(const short8*)(xrow + s * 32);

  const f32x4 zf = {0.f, 0.f, 0.f, 0.f};

  #pragma unroll
  for (int qk = 0; qk < 2; ++qk) {
    const short* W = qk ? WKb : WQb;
    const float* Bs = qk ? BK : BQ;
    short* Outh = qk ? Kh : Qh;
    short* Outl = qk ? Kl : Ql;
    #pragma unroll
    for (int tq = 0; tq < 2; ++tq) {
      f32x4 acc = zf;
      #pragma unroll
      for (int s = 0; s < 8; ++s) {
        short8 bb = *(const short8*)(W + (size_t)(tq * 16 + lr) * CH + s * 32 + g * 8);
        acc = MFMA16(a[s], bb, acc);
      }
      int o = tq * 16 + lr;
      float bias = Bs[o];
      #pragma unroll
      for (int r = 0; r < 4; ++r) {
        int pos = p0 + g * 4 + r;
        float val = acc[r] + bias;
        short hi = f2bf(val);
        Outh[((size_t)b * NN + pos) * D8 + o] = hi;
        Outl[((size_t)b * NN + pos) * D8 + o] = f2bf(val - bf2f(hi));
      }
    }
  }
  #pragma unroll
  for (int tv = 0; tv < 16; ++tv) {
    f32x4 acc = zf;
    #pragma unroll
    for (int s = 0; s < 8; ++s) {
      short8 bb = *(const short8*)(WVb + (size_t)(tv * 16 + lr) * CH + s * 32 + g * 8);
      acc = MFMA16(a[s], bb, acc);
    }
    int o = tv * 16 + lr;
    float bias = BV[o];
    #pragma unroll
    for (int r = 0; r < 4; ++r)
      Vl[o][w * 16 + g * 4 + r] = f2bf(acc[r] + bias);
  }
  __syncthreads();
  int pj = t & 63, orow = t >> 6;
  short* Vb = Vo + (size_t)b * CH * NN + pt * 64 + pj;
  #pragma unroll
  for (int oi = 0; oi < 64; ++oi) {
    int o = orow * 64 + oi;
    Vb[(size_t)o * NN] = Vl[o][pj];              // coalesced 128B stores
  }
}

// ---------------- attn: flash-fused, 64 q/block, KT=64 ----------------
__global__ __launch_bounds__(256) void attn_kernel(
    const short* __restrict__ Qh, const short* __restrict__ Ql,
    const short* __restrict__ Kh, const short* __restrict__ Kl,
    const short* __restrict__ V, const float* __restrict__ x,
    float* __restrict__ out)
{
  int blk = blockIdx.x, t = threadIdx.x;
  // XCD swizzle: 2 XCDs per batch -> per-batch K+V stay L2-resident
  int xcd = blk & 7, idx = blk >> 3;
  int b = xcd >> 1;
  int qt = ((xcd & 1) << 5) + idx;               // 0..63
  int q0 = qt * 64;
  int w = t >> 6, lane = t & 63, g = lane >> 4, lr = lane & 15;
  int cw0 = w * 64;

  union Smem {
    struct {
      short P[2][64 * 64];                       // double-buffered, XOR-swizzled
      float scale[2][64];
      int   flags[2][4];
    } lp;
    float O[CH][67];                             // epilogue transpose buffer
  };
  __shared__ Smem sm;
  __shared__ float l_lds[64];

  const short* Qhb = Qh + (size_t)b * NN * D8;
  const short* Qlb = Ql + (size_t)b * NN * D8;
  const short* Khb = Kh + (size_t)b * NN * D8;
  const short* Klb = Kl + (size_t)b * NN * D8;
  const short* Vb = V + (size_t)b * CH * NN;

  // wave w owns queries [q0+16w, q0+16w+16) for S; all 64 q x 64 ch for O
  short8 aqh = *(const short8*)(Qhb + (size_t)(q0 + w * 16 + lr) * D8 + g * 8);
  short8 aql = *(const short8*)(Qlb + (size_t)(q0 + w * 16 + lr) * D8 + g * 8);

  const f32x4 zf = {0.f, 0.f, 0.f, 0.f};
  f32x4 O[4][4];
  #pragma unroll
  for (int i = 0; i < 4; ++i)
    #pragma unroll
    for (int j = 0; j < 4; ++j) O[i][j] = zf;
  float m[4] = {-INFINITY, -INFINITY, -INFINITY, -INFINITY};
  float l[4] = {0.f, 0.f, 0.f, 0.f};

  char* Pbase0 = (char*)&sm.lp.P[0][0];
  char* Pbase1 = (char*)&sm.lp.P[1][0];

  for (int kb = 0; kb < 64; ++kb) {
    int buf = kb & 1;
    char* Pb = buf ? Pbase1 : Pbase0;
    int k0 = kb * 64;

    // ---- S = Q K^T (16q x 64k), hi/lo split: S = al*bh + ah*bl + ah*bh ----
    f32x4 S[4];
    #pragma unroll
    for (int nt = 0; nt < 4; ++nt) {
      const short* kpos = (const short*)((size_t)(k0 + nt * 16 + lr) * D8 + g * 8);
      short8 bh = *(const short8*)(Khb + (size_t)(k0 + nt * 16 + lr) * D8 + g * 8);
      short8 bl = *(const short8*)(Klb + (size_t)(k0 + nt * 16 + lr) * D8 + g * 8);
      (void)kpos;
      f32x4 s_ = MFMA16(aql, bh, zf);
      s_ = MFMA16(aqh, bl, s_);
      s_ = MFMA16(aqh, bh, s_);
      S[nt] = s_;
    }
    // ---- row max (rows live across 16-lane group) ----
    float sc[4];
    bool upd = false;
    #pragma unroll
    for (int r = 0; r < 4; ++r) {
      float v = fmaxf(fmaxf(S[0][r], S[1][r]), fmaxf(S[2][r], S[3][r]));
      v = fmaxf(v, __shfl_xor(v, 1));
      v = fmaxf(v, __shfl_xor(v, 2));
      v = fmaxf(v, __shfl_xor(v, 4));
      v = fmaxf(v, __shfl_xor(v, 8));
      bool u = v > m[r] + 8.0f;                  // defer-max (T13), P <= 2^8
      upd |= u;
      float mn = u ? v : m[r];
      sc[r] = exp2f(m[r] - mn);                  // ==1 when deferred
      m[r] = mn;
    }
    bool anyupd = __any((int)upd);               // wave-wide (FIX: was lane0-only)
    // ---- P = exp2(S-m), row sum, l update ----
    float rsum[4] = {0.f, 0.f, 0.f, 0.f};
    short pb[4][4];
    #pragma unroll
    for (int nt = 0; nt < 4; ++nt)
      #pragma unroll
      for (int r = 0; r < 4; ++r) {
        float p = exp2f(S[nt][r] - m[r]);
        rsum[r] += p;
        pb[nt][r] = f2bf(p);
      }
    #pragma unroll
    for (int r = 0; r < 4; ++r) {
      float v = rsum[r];
      v += __shfl_xor(v, 1); v += __shfl_xor(v, 2);
      v += __shfl_xor(v, 4); v += __shfl_xor(v, 8);
      l[r] = l[r] * sc[r] + v;
    }
    // ---- publish P (swizzled), scales, update flag ----
    #pragma unroll
    for (int nt = 0; nt < 4; ++nt)
      #pragma unroll
      for (int r = 0; r < 4; ++r) {
        int qloc = w * 16 + g * 4 + r;
        int kk = nt * 16 + lr;
        int off = (qloc * 128 + kk * 2) ^ ((qloc & 7) << 4);
        *(short*)(Pb + off) = pb[nt][r];
      }
    if (lr == 0) {
      #pragma unroll
      for (int r = 0; r < 4; ++r)
        sm.lp.scale[buf][w * 16 + g * 4 + r] = sc[r];
    }
    if (lane == 0) sm.lp.flags[buf][w] = anyupd ? 1 : 0;
    __syncthreads();                             // the ONLY barrier per chunk

    // ---- rescale O (block-uniform skip when no wave updated its max) ----
    int need = sm.lp.flags[buf][0] | sm.lp.flags[buf][1] |
               sm.lp.flags[buf][2] | sm.lp.flags[buf][3];
    if (need) {
      #pragma unroll
      for (int mi = 0; mi < 4; ++mi)
        #pragma unroll
        for (int r = 0; r < 4; ++r) {
          float s = sm.lp.scale[buf][mi * 16 + g * 4 + r];
          #pragma unroll
          for (int ci = 0; ci < 4; ++ci) O[mi][ci][r] *= s;
        }
    }
    // ---- PV: O[64q x 64ch] += P[64q x 64k] * V^T ----
    #pragma unroll
    for (int ss = 0; ss < 2; ++ss) {
      short8 ap[4];
      #pragma unroll
      for (int mi = 0; mi < 4; ++mi) {
        int row = mi * 16 + lr;
        int off = (row * 128 + (ss * 32 + g * 8) * 2) ^ ((row & 7) << 4);
        ap[mi] = *(const short8*)(Pb + off);
      }
      #pragma unroll
      for (int ci = 0; ci < 4; ++ci) {
        short8 bv = *(const short8*)(Vb + (size_t)(cw0 + ci * 16 + lr) * NN
                                     + k0 + ss * 32 + g * 8);
        #pragma unroll
        for (int mi = 0; mi < 4; ++mi)
          O[mi][ci] = MFMA16(ap[mi], bv, O[mi][ci]);
      }
    }
  }

  if (lr == 0) {
    #pragma unroll
    for (int r = 0; r < 4; ++r)
      l_lds[w * 16 + g * 4 + r] = l[r];
  }
  __syncthreads();                               // all P reads done before O reuse
  #pragma unroll
  for (int mi = 0; mi < 4; ++mi)
    #pragma unroll
    for (int ci = 0; ci < 4; ++ci) {
      int ch = cw0 + ci * 16 + lr;
      #pragma unroll
      for (int r = 0; r < 4; ++r)
        sm.O[ch][mi * 16 + g * 4 + r] = O[mi][ci][r];
    }
  __syncthreads();
  int q = t & 63, orow = t >> 6;
  float linv = 1.0f / l_lds[q];
  const float* xb = x + (size_t)b * CH * NN + q0 + q;
  float* ob = out + (size_t)b * CH * NN + q0 + q;
  #pragma unroll
  for (int oi = 0; oi < 64; ++oi) {
    int ch = orow * 64 + oi;
    ob[(size_t)ch * NN] = sm.O[ch][q] * linv + xb[(size_t)ch * NN];
  }
}

extern "C" void kernel_launch(void* const* d_in, const int* in_sizes, int n_in,
                              void* d_out, int out_size, void* d_ws, size_t ws_size,
                              hipStream_t stream) {
  const float* x  = (const float*)d_in[0];
  const float* wq = (const float*)d_in[1];
  const float* bq = (const float*)d_in[2];
  const float* wk = (const float*)d_in[3];
  const float* bk = (const float*)d_in[4];
  const float* wv = (const float*)d_in[5];
  const float* bv = (const float*)d_in[6];
  char* ws = (char*)d_ws;
  // workspace layout (21,136,640 B total)
  short* xT  = (short*)(ws);                     //  8 MB: (b,n,c) bf16
  short* Qh  = (short*)(ws + 8388608);           //  1 MB: (b,n,32) bf16 hi
  short* Ql  = (short*)(ws + 9437184);           //  1 MB: lo
  short* Kh  = (short*)(ws + 10485760);          //  1 MB
  short* Kl  = (short*)(ws + 11534336);          //  1 MB
  short* Vo  = (short*)(ws + 12582912);          //  8 MB: (b,c,n) bf16
  short* WQb = (short*)(ws + 20971520);
  short* WKb = (short*)(ws + 20987904);
  short* WVb = (short*)(ws + 21004288);
  float* BQ  = (float*)(ws + 21135360);
  float* BK  = (float*)(ws + 21135488);
  float* BV  = (float*)(ws + 21135616);

  prep_kernel<<<1032, 256, 0, stream>>>(x, wq, bq, wk, bk, wv, bv,
                                        xT, WQb, WKb, WVb, BQ, BK, BV);
  proj_kernel<<<256, 256, 0, stream>>>(xT, WQb, WKb, WVb, BQ, BK, BV,
                                       Qh, Ql, Kh, Kl, Vo);
  attn_kernel<<<256, 256, 0, stream>>>(Qh, Ql, Kh, Kl, Vo, x, (float*)d_out);
}

// Round 4
// 238.089 us; speedup vs baseline: 1.3888x; 1.3888x over previous
//
#include <hip/hip_runtime.h>
#include <hip/hip_bf16.h>
#include <stdint.h>

#define CH 256
#define D8 32
#define NN 4096

typedef __attribute__((ext_vector_type(8))) short short8;
typedef __attribute__((ext_vector_type(4))) float f32x4;

#define MFMA16(a,b,c) __builtin_amdgcn_mfma_f32_16x16x32_bf16(a,b,c,0,0,0)

static __device__ __forceinline__ short f2bf(float f) {
  union { float f; uint32_t u; } v; v.f = f;
  uint32_t r = v.u + 0x7fffu + ((v.u >> 16) & 1u);
  return (short)(r >> 16);
}
static __device__ __forceinline__ float bf2f(short h) {
  union { float f; uint32_t u; } v; v.u = ((uint32_t)(uint16_t)h) << 16;
  return v.f;
}

// ---------------- prep: x transpose->bf16 + weight convert ----------------
__global__ __launch_bounds__(256) void prep_kernel(
    const float* __restrict__ x,
    const float* __restrict__ wq, const float* __restrict__ bq,
    const float* __restrict__ wk, const float* __restrict__ bk,
    const float* __restrict__ wv, const float* __restrict__ bv,
    short* __restrict__ xT, short* __restrict__ WQb,
    short* __restrict__ WKb, short* __restrict__ WVb,
    float* __restrict__ BQ, float* __restrict__ BK, float* __restrict__ BV)
{
  int blk = blockIdx.x, t = threadIdx.x;
  if (blk >= 1024) {
    int idx = (blk - 1024) * 256 + t;            // 0..2047
    const float LOG2E = 1.4426950408889634f;     // fold into Q so exp2 == exp
    for (int i = idx; i < D8 * CH; i += 2048) WQb[i] = f2bf(wq[i] * LOG2E);
    for (int i = idx; i < D8 * CH; i += 2048) WKb[i] = f2bf(wk[i]);
    for (int i = idx; i < CH * CH; i += 2048) WVb[i] = f2bf(wv[i]);
    if (idx < D8) { BQ[idx] = bq[idx] * LOG2E; BK[idx] = bk[idx]; }
    if (idx < CH) BV[idx] = bv[idx];
    return;
  }
  int b = blk >> 8, ct = (blk >> 6) & 3, nt = blk & 63;
  __shared__ short T[64][65];                    // +1 pad: conflict-free transpose
  int j = t & 63, i0 = t >> 6;
  const float* xb = x + ((size_t)b * CH + ct * 64) * NN + nt * 64;
  #pragma unroll
  for (int k = 0; k < 16; ++k) {
    int i = k * 4 + i0;
    T[i][j] = f2bf(xb[(size_t)i * NN + j]);      // coalesced over n
  }
  __syncthreads();
  short* xTb = xT + ((size_t)b * NN + nt * 64) * CH + ct * 64;
  #pragma unroll
  for (int k = 0; k < 16; ++k) {
    int n = k * 4 + i0;
    xTb[(size_t)n * CH + j] = T[j][n];           // coalesced over c
  }
}

// ---------------- proj: Qhi/lo, Khi/lo (n,32) and V (c,n) in bf16 ----------------
__global__ __launch_bounds__(256) void proj_kernel(
    const short* __restrict__ xT,
    const short* __restrict__ WQb, const short* __restrict__ WKb,
    const short* __restrict__ WVb,
    const float* __restrict__ BQ, const float* __restrict__ BK,
    const float* __restrict__ BV,
    short* __restrict__ Qh, short* __restrict__ Ql,
    short* __restrict__ Kh, short* __restrict__ Kl,
    short* __restrict__ Vo)
{
  int blk = blockIdx.x, t = threadIdx.x;
  int b = blk >> 6, pt = blk & 63;
  int w = t >> 6, lane = t & 63, g = lane >> 4, lr = lane & 15;
  int p0 = pt * 64 + w * 16;
  __shared__ short Vl[CH][66];                   // pad 66: conflict-free

  const short* xrow = xT + ((size_t)b * NN + p0 + lr) * CH + g * 8;
  short8 a[8];
  #pragma unroll
  for (int s = 0; s < 8; ++s) a[s] = *(const short8*)(xrow + s * 32);

  const f32x4 zf = {0.f, 0.f, 0.f, 0.f};

  #pragma unroll
  for (int qk = 0; qk < 2; ++qk) {
    const short* W = qk ? WKb : WQb;
    const float* Bs = qk ? BK : BQ;
    short* Outh = qk ? Kh : Qh;
    short* Outl = qk ? Kl : Ql;
    #pragma unroll
    for (int tq = 0; tq < 2; ++tq) {
      f32x4 acc = zf;
      #pragma unroll
      for (int s = 0; s < 8; ++s) {
        short8 bb = *(const short8*)(W + (size_t)(tq * 16 + lr) * CH + s * 32 + g * 8);
        acc = MFMA16(a[s], bb, acc);
      }
      int o = tq * 16 + lr;
      float bias = Bs[o];
      #pragma unroll
      for (int r = 0; r < 4; ++r) {
        int pos = p0 + g * 4 + r;
        float val = acc[r] + bias;
        short hi = f2bf(val);
        Outh[((size_t)b * NN + pos) * D8 + o] = hi;
        Outl[((size_t)b * NN + pos) * D8 + o] = f2bf(val - bf2f(hi));
      }
    }
  }

  // V projection: software-pipelined B-tile prefetch (latency-bound at 1 blk/CU)
#define VSTEP(TV, CUR, NXT) do { \
    int _tn = ((TV) + 1) & 15; \
    _Pragma("unroll") \
    for (int s = 0; s < 8; ++s) \
      NXT[s] = *(const short8*)(WVb + (size_t)(_tn * 16 + lr) * CH + s * 32 + g * 8); \
    f32x4 acc = zf; \
    _Pragma("unroll") \
    for (int s = 0; s < 8; ++s) acc = MFMA16(a[s], CUR[s], acc); \
    int o = (TV) * 16 + lr; \
    float bias = BV[o]; \
    _Pragma("unroll") \
    for (int r = 0; r < 4; ++r) Vl[o][w * 16 + g * 4 + r] = f2bf(acc[r] + bias); \
  } while (0)

  short8 bA[8], bB[8];
  #pragma unroll
  for (int s = 0; s < 8; ++s)
    bA[s] = *(const short8*)(WVb + (size_t)lr * CH + s * 32 + g * 8);  // tile 0
  #pragma unroll
  for (int tv2 = 0; tv2 < 8; ++tv2) {
    VSTEP(2 * tv2, bA, bB);
    VSTEP(2 * tv2 + 1, bB, bA);
  }
#undef VSTEP

  __syncthreads();
  int pj = t & 63, orow = t >> 6;
  short* Vb = Vo + (size_t)b * CH * NN + pt * 64 + pj;
  #pragma unroll
  for (int oi = 0; oi < 64; ++oi) {
    int o = orow * 64 + oi;
    Vb[(size_t)o * NN] = Vl[o][pj];              // coalesced 128B stores
  }
}

// ---------------- attn: flash-fused, 64 q/block, KT=64, reg-prefetched ----------------
__global__ __launch_bounds__(256) void attn_kernel(
    const short* __restrict__ Qh, const short* __restrict__ Ql,
    const short* __restrict__ Kh, const short* __restrict__ Kl,
    const short* __restrict__ V, const float* __restrict__ x,
    float* __restrict__ out)
{
  int blk = blockIdx.x, t = threadIdx.x;
  // XCD swizzle: 2 XCDs per batch -> per-batch K+V stay L2-resident
  int xcd = blk & 7, idx = blk >> 3;
  int b = xcd >> 1;
  int qt = ((xcd & 1) << 5) + idx;               // 0..63
  int q0 = qt * 64;
  int w = t >> 6, lane = t & 63, g = lane >> 4, lr = lane & 15;
  int cw0 = w * 64;

  union Smem {
    struct {
      short P[2][64 * 64];                       // double-buffered, XOR-swizzled
      float scale[2][64];
      int   flags[2][4];
    } lp;
    float O[CH][67];                             // epilogue transpose buffer
  };
  __shared__ Smem sm;
  __shared__ float l_lds[64];

  const short* Qhb = Qh + (size_t)b * NN * D8;
  const short* Qlb = Ql + (size_t)b * NN * D8;
  const short* Khb = Kh + (size_t)b * NN * D8;
  const short* Klb = Kl + (size_t)b * NN * D8;
  const short* Vb = V + (size_t)b * CH * NN;

  // wave w owns queries [q0+16w, q0+16w+16) for S; all 64 q x 64 ch for O
  short8 aqh = *(const short8*)(Qhb + (size_t)(q0 + w * 16 + lr) * D8 + g * 8);
  short8 aql = *(const short8*)(Qlb + (size_t)(q0 + w * 16 + lr) * D8 + g * 8);

  const f32x4 zf = {0.f, 0.f, 0.f, 0.f};
  f32x4 O[4][4];
  #pragma unroll
  for (int i = 0; i < 4; ++i)
    #pragma unroll
    for (int j = 0; j < 4; ++j) O[i][j] = zf;
  float m[4] = {-INFINITY, -INFINITY, -INFINITY, -INFINITY};
  float l[4] = {0.f, 0.f, 0.f, 0.f};

  char* Pbase0 = (char*)&sm.lp.P[0][0];
  char* Pbase1 = (char*)&sm.lp.P[1][0];

#define LOADK(KH, KL, KIDX) do { \
    int _k0 = (KIDX) * 64; \
    _Pragma("unroll") \
    for (int _nt = 0; _nt < 4; ++_nt) { \
      size_t _off = (size_t)(_k0 + _nt * 16 + lr) * D8 + g * 8; \
      KH[_nt] = *(const short8*)(Khb + _off); \
      KL[_nt] = *(const short8*)(Klb + _off); \
    } \
  } while (0)

#define LOADV(VV, KIDX) do { \
    int _k0 = (KIDX) * 64; \
    _Pragma("unroll") \
    for (int _ss = 0; _ss < 2; ++_ss) \
      _Pragma("unroll") \
      for (int _ci = 0; _ci < 4; ++_ci) \
        VV[_ss * 4 + _ci] = *(const short8*)(Vb + \
            (size_t)(cw0 + _ci * 16 + lr) * NN + _k0 + _ss * 32 + g * 8); \
  } while (0)

  // STEP: compute chunk KB with (KH,KL,VV) regs; prefetch chunk KB+1 into (NKH,NKL,NVV)
#define STEP(KB, KH, KL, VV, NKH, NKL, NVV) do { \
    int _buf = (KB) & 1; \
    char* _Pb = _buf ? Pbase1 : Pbase0; \
    /* S = Q K^T, hi/lo split */ \
    f32x4 S[4]; \
    _Pragma("unroll") \
    for (int nt = 0; nt < 4; ++nt) { \
      f32x4 s_ = MFMA16(aql, KH[nt], zf); \
      s_ = MFMA16(aqh, KL[nt], s_); \
      s_ = MFMA16(aqh, KH[nt], s_); \
      S[nt] = s_; \
    } \
    /* prefetch next chunk's K,V: overlaps softmax+publish+barrier+PV */ \
    int _kn = ((KB) + 1) & 63; \
    LOADK(NKH, NKL, _kn); \
    LOADV(NVV, _kn); \
    /* row max across 16-lane group */ \
    float sc[4]; \
    bool upd = false; \
    _Pragma("unroll") \
    for (int r = 0; r < 4; ++r) { \
      float v = fmaxf(fmaxf(S[0][r], S[1][r]), fmaxf(S[2][r], S[3][r])); \
      v = fmaxf(v, __shfl_xor(v, 1)); \
      v = fmaxf(v, __shfl_xor(v, 2)); \
      v = fmaxf(v, __shfl_xor(v, 4)); \
      v = fmaxf(v, __shfl_xor(v, 8)); \
      bool u = v > m[r] + 8.0f;                  /* defer-max, P <= 2^8 */ \
      upd |= u; \
      float mn = u ? v : m[r]; \
      sc[r] = __builtin_amdgcn_exp2f(m[r] - mn); \
      m[r] = mn; \
    } \
    bool anyupd = __any((int)upd); \
    float rsum[4] = {0.f, 0.f, 0.f, 0.f}; \
    short pb[4][4]; \
    _Pragma("unroll") \
    for (int nt = 0; nt < 4; ++nt) \
      _Pragma("unroll") \
      for (int r = 0; r < 4; ++r) { \
        float p = __builtin_amdgcn_exp2f(S[nt][r] - m[r]); \
        rsum[r] += p; \
        pb[nt][r] = f2bf(p); \
      } \
    _Pragma("unroll") \
    for (int r = 0; r < 4; ++r) { \
      float v = rsum[r]; \
      v += __shfl_xor(v, 1); v += __shfl_xor(v, 2); \
      v += __shfl_xor(v, 4); v += __shfl_xor(v, 8); \
      l[r] = l[r] * sc[r] + v; \
    } \
    /* publish P (swizzled), scales, flag */ \
    _Pragma("unroll") \
    for (int nt = 0; nt < 4; ++nt) \
      _Pragma("unroll") \
      for (int r = 0; r < 4; ++r) { \
        int qloc = w * 16 + g * 4 + r; \
        int kk = nt * 16 + lr; \
        int off = (qloc * 128 + kk * 2) ^ ((qloc & 7) << 4); \
        *(short*)(_Pb + off) = pb[nt][r]; \
      } \
    if (lr == 0) { \
      _Pragma("unroll") \
      for (int r = 0; r < 4; ++r) \
        sm.lp.scale[_buf][w * 16 + g * 4 + r] = sc[r]; \
    } \
    if (lane == 0) sm.lp.flags[_buf][w] = anyupd ? 1 : 0; \
    __syncthreads();                             /* the ONLY barrier per chunk */ \
    int need = sm.lp.flags[_buf][0] | sm.lp.flags[_buf][1] | \
               sm.lp.flags[_buf][2] | sm.lp.flags[_buf][3]; \
    if (need) { \
      _Pragma("unroll") \
      for (int mi = 0; mi < 4; ++mi) \
        _Pragma("unroll") \
        for (int r = 0; r < 4; ++r) { \
          float s = sm.lp.scale[_buf][mi * 16 + g * 4 + r]; \
          _Pragma("unroll") \
          for (int ci = 0; ci < 4; ++ci) O[mi][ci][r] *= s; \
        } \
    } \
    /* PV: O[64q x 64ch] += P * V^T, V already in regs */ \
    _Pragma("unroll") \
    for (int ss = 0; ss < 2; ++ss) { \
      short8 ap[4]; \
      _Pragma("unroll") \
      for (int mi = 0; mi < 4; ++mi) { \
        int row = mi * 16 + lr; \
        int off = (row * 128 + (ss * 32 + g * 8) * 2) ^ ((row & 7) << 4); \
        ap[mi] = *(const short8*)(_Pb + off); \
      } \
      _Pragma("unroll") \
      for (int ci = 0; ci < 4; ++ci) { \
        _Pragma("unroll") \
        for (int mi = 0; mi < 4; ++mi) \
          O[mi][ci] = MFMA16(ap[mi], VV[ss * 4 + ci], O[mi][ci]); \
      } \
    } \
  } while (0)

  short8 khA[4], klA[4], vA[8], khB[4], klB[4], vB[8];
  LOADK(khA, klA, 0);
  LOADV(vA, 0);
  #pragma unroll 1
  for (int kb2 = 0; kb2 < 32; ++kb2) {
    STEP(2 * kb2,     khA, klA, vA, khB, klB, vB);
    STEP(2 * kb2 + 1, khB, klB, vB, khA, klA, vA);
  }
#undef STEP
#undef LOADK
#undef LOADV

  if (lr == 0) {
    #pragma unroll
    for (int r = 0; r < 4; ++r)
      l_lds[w * 16 + g * 4 + r] = l[r];
  }
  __syncthreads();                               // all P reads done before O reuse
  #pragma unroll
  for (int mi = 0; mi < 4; ++mi)
    #pragma unroll
    for (int ci = 0; ci < 4; ++ci) {
      int ch = cw0 + ci * 16 + lr;
      #pragma unroll
      for (int r = 0; r < 4; ++r)
        sm.O[ch][mi * 16 + g * 4 + r] = O[mi][ci][r];
    }
  __syncthreads();
  int q = t & 63, orow = t >> 6;
  float linv = 1.0f / l_lds[q];
  const float* xb = x + (size_t)b * CH * NN + q0 + q;
  float* ob = out + (size_t)b * CH * NN + q0 + q;
  #pragma unroll
  for (int oi = 0; oi < 64; ++oi) {
    int ch = orow * 64 + oi;
    ob[(size_t)ch * NN] = sm.O[ch][q] * linv + xb[(size_t)ch * NN];
  }
}

extern "C" void kernel_launch(void* const* d_in, const int* in_sizes, int n_in,
                              void* d_out, int out_size, void* d_ws, size_t ws_size,
                              hipStream_t stream) {
  const float* x  = (const float*)d_in[0];
  const float* wq = (const float*)d_in[1];
  const float* bq = (const float*)d_in[2];
  const float* wk = (const float*)d_in[3];
  const float* bk = (const float*)d_in[4];
  const float* wv = (const float*)d_in[5];
  const float* bv = (const float*)d_in[6];
  char* ws = (char*)d_ws;
  // workspace layout (21,136,640 B total)
  short* xT  = (short*)(ws);                     //  8 MB: (b,n,c) bf16
  short* Qh  = (short*)(ws + 8388608);           //  1 MB: (b,n,32) bf16 hi
  short* Ql  = (short*)(ws + 9437184);           //  1 MB: lo
  short* Kh  = (short*)(ws + 10485760);          //  1 MB
  short* Kl  = (short*)(ws + 11534336);          //  1 MB
  short* Vo  = (short*)(ws + 12582912);          //  8 MB: (b,c,n) bf16
  short* WQb = (short*)(ws + 20971520);
  short* WKb = (short*)(ws + 20987904);
  short* WVb = (short*)(ws + 21004288);
  float* BQ  = (float*)(ws + 21135360);
  float* BK  = (float*)(ws + 21135488);
  float* BV  = (float*)(ws + 21135616);

  prep_kernel<<<1032, 256, 0, stream>>>(x, wq, bq, wk, bk, wv, bv,
                                        xT, WQb, WKb, WVb, BQ, BK, BV);
  proj_kernel<<<256, 256, 0, stream>>>(xT, WQb, WKb, WVb, BQ, BK, BV,
                                       Qh, Ql, Kh, Kl, Vo);
  attn_kernel<<<256, 256, 0, stream>>>(Qh, Ql, Kh, Kl, Vo, x, (float*)d_out);
}

// Round 6
// 218.348 us; speedup vs baseline: 1.5144x; 1.0904x over previous
//
#include <hip/hip_runtime.h>
#include <hip/hip_bf16.h>
#include <stdint.h>

#define CH 256
#define D8 32
#define NN 4096

typedef __attribute__((ext_vector_type(8))) short short8;
typedef __attribute__((ext_vector_type(4))) short s16x4;
typedef __attribute__((ext_vector_type(4))) float f32x4;

#define MFMA16(a,b,c) __builtin_amdgcn_mfma_f32_16x16x32_bf16(a,b,c,0,0,0)

static __device__ __forceinline__ short f2bf(float f) {
  union { float f; uint32_t u; } v; v.f = f;
  uint32_t r = v.u + 0x7fffu + ((v.u >> 16) & 1u);
  return (short)(r >> 16);
}
static __device__ __forceinline__ float bf2f(short h) {
  union { float f; uint32_t u; } v; v.u = ((uint32_t)(uint16_t)h) << 16;
  return v.f;
}

// ---------------- prep: x transpose->bf16 + weight convert ----------------
__global__ __launch_bounds__(256) void prep_kernel(
    const float* __restrict__ x,
    const float* __restrict__ wq, const float* __restrict__ bq,
    const float* __restrict__ wk, const float* __restrict__ bk,
    const float* __restrict__ wv, const float* __restrict__ bv,
    short* __restrict__ xT, short* __restrict__ WQb,
    short* __restrict__ WKb, short* __restrict__ WVb,
    float* __restrict__ BQ, float* __restrict__ BK, float* __restrict__ BV)
{
  int blk = blockIdx.x, t = threadIdx.x;
  if (blk >= 1024) {
    int idx = (blk - 1024) * 256 + t;            // 0..2047
    const float LOG2E = 1.4426950408889634f;     // fold into Q so exp2 == exp
    for (int i = idx; i < D8 * CH; i += 2048) WQb[i] = f2bf(wq[i] * LOG2E);
    for (int i = idx; i < D8 * CH; i += 2048) WKb[i] = f2bf(wk[i]);
    for (int i = idx; i < CH * CH; i += 2048) WVb[i] = f2bf(wv[i]);
    if (idx < D8) { BQ[idx] = bq[idx] * LOG2E; BK[idx] = bk[idx]; }
    if (idx < CH) BV[idx] = bv[idx];
    return;
  }
  int b = blk >> 8, ct = (blk >> 6) & 3, nt = blk & 63;
  __shared__ short T[64][65];                    // +1 pad: conflict-free transpose
  int j = t & 63, i0 = t >> 6;
  const float* xb = x + ((size_t)b * CH + ct * 64) * NN + nt * 64;
  #pragma unroll
  for (int k = 0; k < 16; ++k) {
    int i = k * 4 + i0;
    T[i][j] = f2bf(xb[(size_t)i * NN + j]);      // coalesced over n
  }
  __syncthreads();
  short* xTb = xT + ((size_t)b * NN + nt * 64) * CH + ct * 64;
  #pragma unroll
  for (int k = 0; k < 16; ++k) {
    int n = k * 4 + i0;
    xTb[(size_t)n * CH + j] = T[j][n];           // coalesced over c
  }
}

// ---------------- proj: 1024 blocks (4/CU), 16 pos/block, 5 tiles/wave ----------------
__global__ __launch_bounds__(256) void proj_kernel(
    const short* __restrict__ xT,
    const short* __restrict__ WQb, const short* __restrict__ WKb,
    const short* __restrict__ WVb,
    const float* __restrict__ BQ, const float* __restrict__ BK,
    const float* __restrict__ BV,
    short* __restrict__ Qh, short* __restrict__ Ql,
    short* __restrict__ Kh, short* __restrict__ Kl,
    short* __restrict__ Vo)
{
  int blk = blockIdx.x, t = threadIdx.x;
  int b = blk >> 8, pt = blk & 255;              // 4 batches x 256 pos-tiles
  int w = t >> 6, lane = t & 63, g = lane >> 4, lr = lane & 15;
  int p0 = pt * 16;
  __shared__ short Vt[4][16][20];                // per-wave transpose buf (stride 20: 8B-aligned rows)

  const short* xrow = xT + ((size_t)b * NN + p0 + lr) * CH + g * 8;
  short8 a[8];
  #pragma unroll
  for (int s = 0; s < 8; ++s) a[s] = *(const short8*)(xrow + s * 32);

  const f32x4 zf = {0.f, 0.f, 0.f, 0.f};

  #pragma unroll
  for (int i = 0; i < 5; ++i) {
    int tt = w * 5 + i;                          // 0..19: 2 Q + 2 K + 16 V tiles
    const short* W; const float* Bs; int tloc;
    if (tt < 2)      { W = WQb; Bs = BQ; tloc = tt; }
    else if (tt < 4) { W = WKb; Bs = BK; tloc = tt - 2; }
    else             { W = WVb; Bs = BV; tloc = tt - 4; }
    f32x4 acc = zf;
    #pragma unroll
    for (int s = 0; s < 8; ++s) {
      short8 bb = *(const short8*)(W + (size_t)(tloc * 16 + lr) * CH + s * 32 + g * 8);
      acc = MFMA16(a[s], bb, acc);
    }
    int o = tloc * 16 + lr;
    float bias = Bs[o];
    if (tt < 4) {
      short* Oh = (tt < 2) ? Qh : Kh;
      short* Ol = (tt < 2) ? Ql : Kl;
      #pragma unroll
      for (int r = 0; r < 4; ++r) {
        int pos = p0 + g * 4 + r;
        float val = acc[r] + bias;
        short hi = f2bf(val);
        Oh[((size_t)b * NN + pos) * D8 + o] = hi;
        Ol[((size_t)b * NN + pos) * D8 + o] = f2bf(val - bf2f(hi));
      }
    } else {
      #pragma unroll
      for (int r = 0; r < 4; ++r)
        Vt[w][lr][g * 4 + r] = f2bf(acc[r] + bias);
      int row = lane >> 2, c4 = (lane & 3) * 4;  // in-wave transpose read
      s16x4 vv = *(const s16x4*)&Vt[w][row][c4];
      *(s16x4*)(Vo + ((size_t)b * CH + tloc * 16 + row) * NN + p0 + c4) = vv;
    }
  }
}

// -------- attn: flash-fused, 64 q/block, KT=64, 8 waves (4 S-role + 4 PV-role) --------
__global__ __launch_bounds__(512) void attn_kernel(
    const short* __restrict__ Qh, const short* __restrict__ Ql,
    const short* __restrict__ Kh, const short* __restrict__ Kl,
    const short* __restrict__ V, const float* __restrict__ x,
    float* __restrict__ out)
{
  int blk = blockIdx.x, t = threadIdx.x;
  // XCD swizzle: 2 XCDs per batch -> per-batch K+V stay L2-resident
  int xcd = blk & 7, idx = blk >> 3;
  int b = xcd >> 1;
  int qt = ((xcd & 1) << 5) + idx;               // 0..63
  int q0 = qt * 64;
  int w = t >> 6, lane = t & 63, g = lane >> 4, lr = lane & 15;
  int wS = w & 3;
  bool isS = (w < 4);                            // waves 0-3: S+softmax+publish; 4-7: PV-only
  int cw0 = w * 32;                              // 8 waves x 32 channels

  union Smem {
    struct {
      short P[2][64 * 64];                       // double-buffered, XOR-swizzled
      float scale[2][64];
      int   flags[2][4];
    } lp;
    float O[CH][67];                             // epilogue transpose buffer
  };
  __shared__ Smem sm;
  __shared__ float l_lds[64];

  const short* Qhb = Qh + (size_t)b * NN * D8;
  const short* Qlb = Ql + (size_t)b * NN * D8;
  const short* Khb = Kh + (size_t)b * NN * D8;
  const short* Klb = Kl + (size_t)b * NN * D8;
  const short* Vb = V + (size_t)b * CH * NN;

  short8 aqh, aql;
  if (isS) {
    aqh = *(const short8*)(Qhb + (size_t)(q0 + wS * 16 + lr) * D8 + g * 8);
    aql = *(const short8*)(Qlb + (size_t)(q0 + wS * 16 + lr) * D8 + g * 8);
  }

  const f32x4 zf = {0.f, 0.f, 0.f, 0.f};
  f32x4 O[4][2];                                 // 64q x 32ch per wave
  #pragma unroll
  for (int i = 0; i < 4; ++i)
    #pragma unroll
    for (int j = 0; j < 2; ++j) O[i][j] = zf;
  float m[4] = {-INFINITY, -INFINITY, -INFINITY, -INFINITY};
  float l[4] = {0.f, 0.f, 0.f, 0.f};

  char* Pbase0 = (char*)&sm.lp.P[0][0];
  char* Pbase1 = (char*)&sm.lp.P[1][0];

#define LOADK(KH, KL, KIDX) do { \
    int _k0 = (KIDX) * 64; \
    _Pragma("unroll") \
    for (int _nt = 0; _nt < 4; ++_nt) { \
      size_t _off = (size_t)(_k0 + _nt * 16 + lr) * D8 + g * 8; \
      KH[_nt] = *(const short8*)(Khb + _off); \
      KL[_nt] = *(const short8*)(Klb + _off); \
    } \
  } while (0)

#define LOADV(VV, KIDX) do { \
    int _k0 = (KIDX) * 64; \
    _Pragma("unroll") \
    for (int _ss = 0; _ss < 2; ++_ss) \
      _Pragma("unroll") \
      for (int _ci = 0; _ci < 2; ++_ci) \
        VV[_ss * 2 + _ci] = *(const short8*)(Vb + \
            (size_t)(cw0 + _ci * 16 + lr) * NN + _k0 + _ss * 32 + g * 8); \
  } while (0)

  // STEP: compute chunk KB; prefetch chunk KB+1 into (NKH,NKL,NVV)
#define STEP(KB, KH, KL, VV, NKH, NKL, NVV) do { \
    int _buf = (KB) & 1; \
    char* _Pb = _buf ? Pbase1 : Pbase0; \
    int _kn = ((KB) + 1) & 63; \
    if (isS) { \
      /* S = Q K^T (16q x 64k), hi/lo split */ \
      f32x4 S[4]; \
      _Pragma("unroll") \
      for (int nt = 0; nt < 4; ++nt) { \
        f32x4 s_ = MFMA16(aql, KH[nt], zf); \
        s_ = MFMA16(aqh, KL[nt], s_); \
        s_ = MFMA16(aqh, KH[nt], s_); \
        S[nt] = s_; \
      } \
      LOADK(NKH, NKL, _kn); \
      LOADV(NVV, _kn); \
      /* row max across 16-lane group */ \
      float sc[4]; \
      bool upd = false; \
      _Pragma("unroll") \
      for (int r = 0; r < 4; ++r) { \
        float v = fmaxf(fmaxf(S[0][r], S[1][r]), fmaxf(S[2][r], S[3][r])); \
        v = fmaxf(v, __shfl_xor(v, 1)); \
        v = fmaxf(v, __shfl_xor(v, 2)); \
        v = fmaxf(v, __shfl_xor(v, 4)); \
        v = fmaxf(v, __shfl_xor(v, 8)); \
        bool u = v > m[r] + 8.0f;                /* defer-max, P <= 2^8 */ \
        upd |= u; \
        float mn = u ? v : m[r]; \
        sc[r] = __builtin_amdgcn_exp2f(m[r] - mn); \
        m[r] = mn; \
      } \
      bool anyupd = __any((int)upd); \
      float rsum[4] = {0.f, 0.f, 0.f, 0.f}; \
      short pb[4][4]; \
      _Pragma("unroll") \
      for (int nt = 0; nt < 4; ++nt) \
        _Pragma("unroll") \
        for (int r = 0; r < 4; ++r) { \
          float p = __builtin_amdgcn_exp2f(S[nt][r] - m[r]); \
          rsum[r] += p; \
          pb[nt][r] = f2bf(p); \
        } \
      _Pragma("unroll") \
      for (int r = 0; r < 4; ++r) { \
        float v = rsum[r]; \
        v += __shfl_xor(v, 1); v += __shfl_xor(v, 2); \
        v += __shfl_xor(v, 4); v += __shfl_xor(v, 8); \
        l[r] = l[r] * sc[r] + v; \
      } \
      /* publish P (swizzled), scales, flag */ \
      _Pragma("unroll") \
      for (int nt = 0; nt < 4; ++nt) \
        _Pragma("unroll") \
        for (int r = 0; r < 4; ++r) { \
          int qloc = wS * 16 + g * 4 + r; \
          int kk = nt * 16 + lr; \
          int off = (qloc * 128 + kk * 2) ^ ((qloc & 7) << 4); \
          *(short*)(_Pb + off) = pb[nt][r]; \
        } \
      if (lr == 0) { \
        _Pragma("unroll") \
        for (int r = 0; r < 4; ++r) \
          sm.lp.scale[_buf][wS * 16 + g * 4 + r] = sc[r]; \
      } \
      if (lane == 0) sm.lp.flags[_buf][wS] = anyupd ? 1 : 0; \
    } else { \
      LOADV(NVV, _kn); \
    } \
    __syncthreads();                             /* the ONLY barrier per chunk */ \
    int need = sm.lp.flags[_buf][0] | sm.lp.flags[_buf][1] | \
               sm.lp.flags[_buf][2] | sm.lp.flags[_buf][3]; \
    if (need) { \
      _Pragma("unroll") \
      for (int mi = 0; mi < 4; ++mi) \
        _Pragma("unroll") \
        for (int r = 0; r < 4; ++r) { \
          float s = sm.lp.scale[_buf][mi * 16 + g * 4 + r]; \
          _Pragma("unroll") \
          for (int ci = 0; ci < 2; ++ci) O[mi][ci][r] *= s; \
        } \
    } \
    /* PV: O[64q x 32ch] += P * V^T, V already in regs */ \
    __builtin_amdgcn_s_setprio(1); \
    _Pragma("unroll") \
    for (int ss = 0; ss < 2; ++ss) { \
      short8 ap[4]; \
      _Pragma("unroll") \
      for (int mi = 0; mi < 4; ++mi) { \
        int row = mi * 16 + lr; \
        int off = (row * 128 + (ss * 32 + g * 8) * 2) ^ ((row & 7) << 4); \
        ap[mi] = *(const short8*)(_Pb + off); \
      } \
      _Pragma("unroll") \
      for (int ci = 0; ci < 2; ++ci) { \
        _Pragma("unroll") \
        for (int mi = 0; mi < 4; ++mi) \
          O[mi][ci] = MFMA16(ap[mi], VV[ss * 2 + ci], O[mi][ci]); \
      } \
    } \
    __builtin_amdgcn_s_setprio(0); \
  } while (0)

  short8 khA[4], klA[4], vA[4], khB[4], klB[4], vB[4];
  if (isS) LOADK(khA, klA, 0);
  LOADV(vA, 0);
  #pragma unroll 1
  for (int kb2 = 0; kb2 < 32; ++kb2) {
    STEP(2 * kb2,     khA, klA, vA, khB, klB, vB);
    STEP(2 * kb2 + 1, khB, klB, vB, khA, klA, vA);
  }
#undef STEP
#undef LOADK
#undef LOADV

  if (isS && lr == 0) {
    #pragma unroll
    for (int r = 0; r < 4; ++r)
      l_lds[wS * 16 + g * 4 + r] = l[r];
  }
  __syncthreads();                               // all P reads done before O reuse
  #pragma unroll
  for (int mi = 0; mi < 4; ++mi)
    #pragma unroll
    for (int ci = 0; ci < 2; ++ci) {
      int ch = cw0 + ci * 16 + lr;
      #pragma unroll
      for (int r = 0; r < 4; ++r)
        sm.O[ch][mi * 16 + g * 4 + r] = O[mi][ci][r];
    }
  __syncthreads();
  int q = t & 63, crow = t >> 6;                 // 512 threads: 8 ch-rows x 64 q
  float linv = 1.0f / l_lds[q];
  const float* xb = x + (size_t)b * CH * NN + q0 + q;
  float* ob = out + (size_t)b * CH * NN + q0 + q;
  #pragma unroll
  for (int oi = 0; oi < 32; ++oi) {
    int ch = crow * 32 + oi;
    ob[(size_t)ch * NN] = sm.O[ch][q] * linv + xb[(size_t)ch * NN];
  }
}

extern "C" void kernel_launch(void* const* d_in, const int* in_sizes, int n_in,
                              void* d_out, int out_size, void* d_ws, size_t ws_size,
                              hipStream_t stream) {
  const float* x  = (const float*)d_in[0];
  const float* wq = (const float*)d_in[1];
  const float* bq = (const float*)d_in[2];
  const float* wk = (const float*)d_in[3];
  const float* bk = (const float*)d_in[4];
  const float* wv = (const float*)d_in[5];
  const float* bv = (const float*)d_in[6];
  char* ws = (char*)d_ws;
  // workspace layout (21,136,640 B total)
  short* xT  = (short*)(ws);                     //  8 MB: (b,n,c) bf16
  short* Qh  = (short*)(ws + 8388608);           //  1 MB: (b,n,32) bf16 hi
  short* Ql  = (short*)(ws + 9437184);           //  1 MB: lo
  short* Kh  = (short*)(ws + 10485760);          //  1 MB
  short* Kl  = (short*)(ws + 11534336);          //  1 MB
  short* Vo  = (short*)(ws + 12582912);          //  8 MB: (b,c,n) bf16
  short* WQb = (short*)(ws + 20971520);
  short* WKb = (short*)(ws + 20987904);
  short* WVb = (short*)(ws + 21004288);
  float* BQ  = (float*)(ws + 21135360);
  float* BK  = (float*)(ws + 21135488);
  float* BV  = (float*)(ws + 21135616);

  prep_kernel<<<1032, 256, 0, stream>>>(x, wq, bq, wk, bk, wv, bv,
                                        xT, WQb, WKb, WVb, BQ, BK, BV);
  proj_kernel<<<1024, 256, 0, stream>>>(xT, WQb, WKb, WVb, BQ, BK, BV,
                                        Qh, Ql, Kh, Kl, Vo);
  attn_kernel<<<256, 512, 0, stream>>>(Qh, Ql, Kh, Kl, Vo, x, (float*)d_out);
}